// Round 2
// baseline (842.551 us; speedup 1.0000x reference)
//
#include <hip/hip_runtime.h>
#include <math.h>

#define N_NODES 10000
#define E_EDGES 320000
#define IN_DIM 128
#define EMB 128
#define HID 64
#define NEG_SLOPE 0.2f

// ---------------------------------------------------------------------------
// Kernel A: h = relu(x @ dense_w + b); z = h @ gat_w; a_src = z.att_src;
// a_dst = z.att_dst.  8 rows per 128-thread block; weights read once/block.
// ---------------------------------------------------------------------------
__global__ __launch_bounds__(128) void dense_gat_kernel(
    const float* __restrict__ x, const float* __restrict__ dw,
    const float* __restrict__ db, const float* __restrict__ gw,
    const float* __restrict__ asv, const float* __restrict__ adv,
    float* __restrict__ z, float* __restrict__ a_src, float* __restrict__ a_dst)
{
    __shared__ float xs[8][IN_DIM];
    __shared__ float hs[8][EMB];
    const int t = threadIdx.x;
    const int row0 = blockIdx.x * 8;   // 10000 % 8 == 0, no guards needed

    #pragma unroll
    for (int r = 0; r < 8; ++r)
        xs[r][t] = x[(row0 + r) * IN_DIM + t];
    __syncthreads();

    float acc[8];
    {
        const float bias = db[t];
        #pragma unroll
        for (int r = 0; r < 8; ++r) acc[r] = bias;
    }
    for (int j = 0; j < IN_DIM; ++j) {
        const float wj = dw[j * EMB + t];
        #pragma unroll
        for (int r = 0; r < 8; ++r) acc[r] = fmaf(xs[r][j], wj, acc[r]);
    }
    #pragma unroll
    for (int r = 0; r < 8; ++r) hs[r][t] = fmaxf(acc[r], 0.f);
    __syncthreads();

    if (t < HID) {   // wave 0 only
        float zacc[8];
        #pragma unroll
        for (int r = 0; r < 8; ++r) zacc[r] = 0.f;
        for (int k = 0; k < EMB; ++k) {
            const float g = gw[k * HID + t];
            #pragma unroll
            for (int r = 0; r < 8; ++r) zacc[r] = fmaf(hs[r][k], g, zacc[r]);
        }
        const float as = asv[t], ad = adv[t];
        #pragma unroll
        for (int r = 0; r < 8; ++r) {
            const int row = row0 + r;
            z[row * HID + t] = zacc[r];
            float ps = zacc[r] * as;
            float pd = zacc[r] * ad;
            #pragma unroll
            for (int off = 32; off > 0; off >>= 1) {
                ps += __shfl_down(ps, off, 64);
                pd += __shfl_down(pd, off, 64);
            }
            if (t == 0) { a_src[row] = ps; a_dst[row] = pd; }
        }
    }
}

// ---------------------------------------------------------------------------
// Kernel B: per-edge softmax weights + atomic aggregation.
// One wave (64 lanes) per edge; lane = feature dim.  Softmax max-shift is
// skipped: e is bounded (|e| < ~8), exp() safe in fp32, alpha invariant.
// edge_index is int32 on-device (harness converts all integer inputs).
// ---------------------------------------------------------------------------
__global__ __launch_bounds__(256) void edge_kernel(
    const int* __restrict__ ei, const float* __restrict__ a_src,
    const float* __restrict__ a_dst, const float* __restrict__ z,
    float* __restrict__ denom, float* __restrict__ embed_u)
{
    const int gtid = blockIdx.x * blockDim.x + threadIdx.x;
    const int edge = gtid >> 6;
    const int lane = gtid & 63;
    const int total = E_EDGES + N_NODES;
    if (edge >= total) return;

    int s, d;
    if (edge < E_EDGES) {
        s = ei[edge];
        d = ei[E_EDGES + edge];
    } else {
        s = d = edge - E_EDGES;   // self loop
    }
    // defensive clamp: wrong numbers beat a device abort
    if ((unsigned)s >= N_NODES || (unsigned)d >= N_NODES) return;

    float e = a_src[s] + a_dst[d];
    e = (e > 0.f) ? e : NEG_SLOPE * e;
    const float w = __expf(e);

    atomicAdd(&embed_u[d * HID + lane], w * z[s * HID + lane]);
    if (lane == 0) atomicAdd(&denom[d], w);
}

// ---------------------------------------------------------------------------
// Kernel C: embed_x = embed_u / denom + gat_b
// ---------------------------------------------------------------------------
__global__ __launch_bounds__(256) void norm_kernel(
    const float* __restrict__ eu, const float* __restrict__ denom,
    const float* __restrict__ gb, float* __restrict__ emb)
{
    const int tid = blockIdx.x * blockDim.x + threadIdx.x;
    if (tid >= N_NODES * HID) return;
    emb[tid] = eu[tid] / denom[tid >> 6] + gb[tid & 63];
}

// ---------------------------------------------------------------------------
// Kernel D: sim = sigmoid(emb @ emb^T).  128x128 tile, 8x8 per thread,
// K=64 processed in two 32-chunks.  LDS stride 33 -> banks (r+k)&31;
// row assignment i*16+ty / col j*16+tx -> conflict-free reads.
// ---------------------------------------------------------------------------
#define TILE 128
__global__ __launch_bounds__(256) void sim_kernel(
    const float* __restrict__ emb, float* __restrict__ sim)
{
    __shared__ float As[TILE * 33];
    __shared__ float Bs[TILE * 33];
    const int t = threadIdx.x;
    const int rowBase = blockIdx.y * TILE;
    const int colBase = blockIdx.x * TILE;
    const int tx = t & 15, ty = t >> 4;

    float acc[8][8];
    #pragma unroll
    for (int i = 0; i < 8; ++i)
        #pragma unroll
        for (int j = 0; j < 8; ++j) acc[i][j] = 0.f;

    for (int kk = 0; kk < 64; kk += 32) {
        __syncthreads();
        #pragma unroll
        for (int i = 0; i < 16; ++i) {
            const int l = t + i * 256;
            const int r = l >> 5, c = l & 31;
            const int gr = rowBase + r;
            As[r * 33 + c] = (gr < N_NODES) ? emb[gr * 64 + kk + c] : 0.f;
            const int gc = colBase + r;
            Bs[r * 33 + c] = (gc < N_NODES) ? emb[gc * 64 + kk + c] : 0.f;
        }
        __syncthreads();

        for (int k = 0; k < 32; ++k) {
            float a[8], b[8];
            #pragma unroll
            for (int i = 0; i < 8; ++i) a[i] = As[(i * 16 + ty) * 33 + k];
            #pragma unroll
            for (int j = 0; j < 8; ++j) b[j] = Bs[(j * 16 + tx) * 33 + k];
            #pragma unroll
            for (int i = 0; i < 8; ++i)
                #pragma unroll
                for (int j = 0; j < 8; ++j)
                    acc[i][j] = fmaf(a[i], b[j], acc[i][j]);
        }
    }

    #pragma unroll
    for (int i = 0; i < 8; ++i) {
        const int gr = rowBase + i * 16 + ty;
        if (gr >= N_NODES) continue;
        const size_t rowoff = (size_t)gr * N_NODES;
        #pragma unroll
        for (int j = 0; j < 8; ++j) {
            const int gc = colBase + j * 16 + tx;
            if (gc < N_NODES) {
                const float v = acc[i][j];
                sim[rowoff + gc] = 1.f / (1.f + __expf(-v));
            }
        }
    }
}

// ---------------------------------------------------------------------------
extern "C" void kernel_launch(void* const* d_in, const int* in_sizes, int n_in,
                              void* d_out, int out_size, void* d_ws, size_t ws_size,
                              hipStream_t stream)
{
    const float* x   = (const float*)d_in[0];
    const int*   ei  = (const int*)d_in[1];   // edge_index as int32 [2,E]
    const float* dw  = (const float*)d_in[2];
    const float* db  = (const float*)d_in[3];
    const float* gw  = (const float*)d_in[4];
    const float* asv = (const float*)d_in[5];
    const float* adv = (const float*)d_in[6];
    const float* gb  = (const float*)d_in[7];

    float* out = (float*)d_out;
    float* sim = out;                                   // [N*N]
    float* emb = out + (size_t)N_NODES * N_NODES;       // [N*HID]

    // Scratch layout (floats): z 640000 | a_src 10000 | a_dst 10000 |
    // denom 10000 | embed_u 640000  => 1,310,000 floats (5.24 MB).
    // If ws is too small, carve from the sim region (dead until sim_kernel).
    const size_t need = 1310000 * sizeof(float);
    float* ws = (ws_size >= need) ? (float*)d_ws : out;
    float* z       = ws;
    float* a_src   = ws + 640000;
    float* a_dst   = ws + 650000;
    float* denom   = ws + 660000;
    float* embed_u = ws + 670000;

    // denom + embed_u must be zero every call (ws is poisoned 0xAA).
    hipMemsetAsync(denom, 0, 650000 * sizeof(float), stream);

    dense_gat_kernel<<<N_NODES / 8, 128, 0, stream>>>(x, dw, db, gw, asv, adv,
                                                      z, a_src, a_dst);

    const int total_edges = E_EDGES + N_NODES;
    const int edge_blocks = (total_edges * 64 + 255) / 256;
    edge_kernel<<<edge_blocks, 256, 0, stream>>>(ei, a_src, a_dst, z,
                                                 denom, embed_u);

    norm_kernel<<<(N_NODES * HID + 255) / 256, 256, 0, stream>>>(embed_u, denom,
                                                                 gb, emb);

    dim3 grid((N_NODES + TILE - 1) / TILE, (N_NODES + TILE - 1) / TILE);
    sim_kernel<<<grid, 256, 0, stream>>>(emb, sim);
}

// Round 3
// 580.975 us; speedup vs baseline: 1.4502x; 1.4502x over previous
//
#include <hip/hip_runtime.h>
#include <math.h>

#define N_NODES 10000
#define E_EDGES 320000
#define IN_DIM 128
#define EMB 128
#define HID 64
#define NEG_SLOPE 0.2f

typedef __attribute__((ext_vector_type(8))) short short8;     // 8 bf16 (4 VGPR)
typedef __attribute__((ext_vector_type(4))) float floatx4;    // 4 fp32

// fp32 -> bf16 bits, round-to-nearest-even
__device__ __forceinline__ short f2bf(float f) {
    unsigned u = __float_as_uint(f);
    unsigned r = u + 0x7fffu + ((u >> 16) & 1u);
    return (short)(r >> 16);
}

// ---------------------------------------------------------------------------
// Kernel A: h = relu(x @ dense_w + b); z = h @ gat_w; a_src/a_dst dots.
// ---------------------------------------------------------------------------
__global__ __launch_bounds__(128) void dense_gat_kernel(
    const float* __restrict__ x, const float* __restrict__ dw,
    const float* __restrict__ db, const float* __restrict__ gw,
    const float* __restrict__ asv, const float* __restrict__ adv,
    float* __restrict__ z, float* __restrict__ a_src, float* __restrict__ a_dst)
{
    __shared__ float xs[8][IN_DIM];
    __shared__ float hs[8][EMB];
    const int t = threadIdx.x;
    const int row0 = blockIdx.x * 8;   // 10000 % 8 == 0

    #pragma unroll
    for (int r = 0; r < 8; ++r)
        xs[r][t] = x[(row0 + r) * IN_DIM + t];
    __syncthreads();

    float acc[8];
    {
        const float bias = db[t];
        #pragma unroll
        for (int r = 0; r < 8; ++r) acc[r] = bias;
    }
    for (int j = 0; j < IN_DIM; ++j) {
        const float wj = dw[j * EMB + t];
        #pragma unroll
        for (int r = 0; r < 8; ++r) acc[r] = fmaf(xs[r][j], wj, acc[r]);
    }
    #pragma unroll
    for (int r = 0; r < 8; ++r) hs[r][t] = fmaxf(acc[r], 0.f);
    __syncthreads();

    if (t < HID) {   // wave 0 only
        float zacc[8];
        #pragma unroll
        for (int r = 0; r < 8; ++r) zacc[r] = 0.f;
        for (int k = 0; k < EMB; ++k) {
            const float g = gw[k * HID + t];
            #pragma unroll
            for (int r = 0; r < 8; ++r) zacc[r] = fmaf(hs[r][k], g, zacc[r]);
        }
        const float as = asv[t], ad = adv[t];
        #pragma unroll
        for (int r = 0; r < 8; ++r) {
            const int row = row0 + r;
            z[row * HID + t] = zacc[r];
            float ps = zacc[r] * as;
            float pd = zacc[r] * ad;
            #pragma unroll
            for (int off = 32; off > 0; off >>= 1) {
                ps += __shfl_down(ps, off, 64);
                pd += __shfl_down(pd, off, 64);
            }
            if (t == 0) { a_src[row] = ps; a_dst[row] = pd; }
        }
    }
}

// ---------------------------------------------------------------------------
// Edge pipeline: counting sort by dst, then atomic-free aggregation.
// ---------------------------------------------------------------------------
__global__ __launch_bounds__(256) void count_kernel(
    const int* __restrict__ ei, int* __restrict__ cnt)
{
    const int e = blockIdx.x * blockDim.x + threadIdx.x;
    const int total = E_EDGES + N_NODES;
    if (e >= total) return;
    int s, d;
    if (e < E_EDGES) { s = ei[e]; d = ei[E_EDGES + e]; }
    else             { s = d = e - E_EDGES; }
    if ((unsigned)s >= N_NODES || (unsigned)d >= N_NODES) return;
    atomicAdd(&cnt[d], 1);
}

// single block, 256 threads, 40 items each (10240 >= 10000)
__global__ __launch_bounds__(256) void scan_kernel(
    const int* __restrict__ cnt, int* __restrict__ offs, int* __restrict__ cursor)
{
    __shared__ int part[256];
    const int t = threadIdx.x;
    const int base = t * 40;
    int vals[40];
    int local = 0;
    #pragma unroll
    for (int i = 0; i < 40; ++i) {
        const int idx = base + i;
        const int c = (idx < N_NODES) ? cnt[idx] : 0;
        vals[i] = c;
        local += c;
    }
    part[t] = local;
    __syncthreads();
    for (int off = 1; off < 256; off <<= 1) {   // Hillis-Steele inclusive
        const int v = (t >= off) ? part[t - off] : 0;
        __syncthreads();
        part[t] += v;
        __syncthreads();
    }
    int running = (t == 0) ? 0 : part[t - 1];   // exclusive base
    #pragma unroll
    for (int i = 0; i < 40; ++i) {
        const int idx = base + i;
        if (idx < N_NODES) { offs[idx] = running; cursor[idx] = running; }
        running += vals[i];
    }
    if (t == 255) offs[N_NODES] = running;
}

__global__ __launch_bounds__(256) void scatter_kernel(
    const int* __restrict__ ei, const float* __restrict__ a_src,
    const float* __restrict__ a_dst, int* __restrict__ cursor,
    int* __restrict__ srcs, float* __restrict__ ew)
{
    const int e = blockIdx.x * blockDim.x + threadIdx.x;
    const int total = E_EDGES + N_NODES;
    if (e >= total) return;
    int s, d;
    if (e < E_EDGES) { s = ei[e]; d = ei[E_EDGES + e]; }
    else             { s = d = e - E_EDGES; }
    if ((unsigned)s >= N_NODES || (unsigned)d >= N_NODES) return;
    float v = a_src[s] + a_dst[d];
    v = (v > 0.f) ? v : NEG_SLOPE * v;
    const float w = __expf(v);          // max-shift skipped: |v| small, fp32 safe
    const int pos = atomicAdd(&cursor[d], 1);
    srcs[pos] = s;
    ew[pos]   = w;
}

// one wave per node; lane = feature dim. No atomics.
__global__ __launch_bounds__(256) void aggregate_kernel(
    const int* __restrict__ offs, const int* __restrict__ srcs,
    const float* __restrict__ ew, const float* __restrict__ z,
    const float* __restrict__ gb, float* __restrict__ emb)
{
    const int wid  = (blockIdx.x * blockDim.x + threadIdx.x) >> 6;
    const int lane = threadIdx.x & 63;
    if (wid >= N_NODES) return;
    const int beg = offs[wid], end = offs[wid + 1];
    float acc = 0.f, sw = 0.f;
    for (int i = beg; i < end; ++i) {
        const int s   = srcs[i];        // broadcast across the wave
        const float w = ew[i];
        acc = fmaf(w, z[s * HID + lane], acc);
        sw += w;
    }
    emb[wid * HID + lane] = acc / sw + gb[lane];  // every node has a self loop
}

// ---------------------------------------------------------------------------
// Kernel D: sim = sigmoid(emb @ emb^T) via bf16 MFMA. 128x128 block tile,
// 4 waves of 64x64 (4x4 subtiles of 16x16x32). No LDS: emb is 2.56 MB,
// L2-resident; fragments loaded from global + converted fp32->bf16 on the fly.
// A frag: A[m=lane&15][k=quad*8+j]; B frag: B[k=quad*8+j][n=lane&15] =
// emb[n][k] (same pattern as A). C/D: col=lane&15, row=quad*4+reg. [m89]
// ---------------------------------------------------------------------------
__global__ __launch_bounds__(256) void sim_kernel(
    const float* __restrict__ emb, float* __restrict__ sim)
{
    const int t    = threadIdx.x;
    const int lane = t & 63;
    const int wave = t >> 6;                 // 0..3
    const int wm   = (wave >> 1) * 64;
    const int wn   = (wave & 1) * 64;
    const int rowBase = blockIdx.y * 128 + wm;
    const int colBase = blockIdx.x * 128 + wn;
    const int l15  = lane & 15;
    const int quad = lane >> 4;              // 0..3

    short8 afrag[4][2], bfrag[4][2];
    #pragma unroll
    for (int ti = 0; ti < 4; ++ti) {
        int r = rowBase + ti * 16 + l15; if (r > N_NODES - 1) r = N_NODES - 1;
        int c = colBase + ti * 16 + l15; if (c > N_NODES - 1) c = N_NODES - 1;
        #pragma unroll
        for (int ks = 0; ks < 2; ++ks) {
            const floatx4* pa = (const floatx4*)&emb[r * HID + ks * 32 + quad * 8];
            const floatx4* pb = (const floatx4*)&emb[c * HID + ks * 32 + quad * 8];
            const floatx4 a0 = pa[0], a1 = pa[1];
            const floatx4 b0 = pb[0], b1 = pb[1];
            short8 af, bf;
            #pragma unroll
            for (int j = 0; j < 4; ++j) { af[j] = f2bf(a0[j]); af[4 + j] = f2bf(a1[j]); }
            #pragma unroll
            for (int j = 0; j < 4; ++j) { bf[j] = f2bf(b0[j]); bf[4 + j] = f2bf(b1[j]); }
            afrag[ti][ks] = af;
            bfrag[ti][ks] = bf;
        }
    }

    floatx4 acc[4][4];
    const floatx4 zero = {0.f, 0.f, 0.f, 0.f};
    #pragma unroll
    for (int ti = 0; ti < 4; ++ti)
        #pragma unroll
        for (int tj = 0; tj < 4; ++tj) acc[ti][tj] = zero;

    #pragma unroll
    for (int ti = 0; ti < 4; ++ti)
        #pragma unroll
        for (int tj = 0; tj < 4; ++tj) {
            acc[ti][tj] = __builtin_amdgcn_mfma_f32_16x16x32_bf16(
                afrag[ti][0], bfrag[tj][0], acc[ti][tj], 0, 0, 0);
            acc[ti][tj] = __builtin_amdgcn_mfma_f32_16x16x32_bf16(
                afrag[ti][1], bfrag[tj][1], acc[ti][tj], 0, 0, 0);
        }

    #pragma unroll
    for (int ti = 0; ti < 4; ++ti) {
        #pragma unroll
        for (int reg = 0; reg < 4; ++reg) {
            const int gr = rowBase + ti * 16 + quad * 4 + reg;
            if (gr >= N_NODES) continue;
            const size_t rowoff = (size_t)gr * N_NODES;
            #pragma unroll
            for (int tj = 0; tj < 4; ++tj) {
                const int gc = colBase + tj * 16 + l15;
                if (gc < N_NODES) {
                    const float v = acc[ti][tj][reg];
                    sim[rowoff + gc] = __builtin_amdgcn_rcpf(1.f + __expf(-v));
                }
            }
        }
    }
}

// ---------------------------------------------------------------------------
extern "C" void kernel_launch(void* const* d_in, const int* in_sizes, int n_in,
                              void* d_out, int out_size, void* d_ws, size_t ws_size,
                              hipStream_t stream)
{
    const float* x   = (const float*)d_in[0];
    const int*   ei  = (const int*)d_in[1];   // edge_index int32 [2,E]
    const float* dw  = (const float*)d_in[2];
    const float* db  = (const float*)d_in[3];
    const float* gw  = (const float*)d_in[4];
    const float* asv = (const float*)d_in[5];
    const float* adv = (const float*)d_in[6];
    const float* gb  = (const float*)d_in[7];

    float* out = (float*)d_out;
    float* sim = out;                                   // [N*N]
    float* emb = out + (size_t)N_NODES * N_NODES;       // [N*HID]

    // Scratch (floats/ints, all dead before sim_kernel):
    // z 640000 | a_src 10000 | a_dst 10000 | cnt 10000 | offs 10001 |
    // cursor 10000 | srcs 330000 | ew 330000  => 1,350,001 * 4B ~= 5.4 MB
    const size_t need = 1350001u * sizeof(float);
    float* ws = (ws_size >= need) ? (float*)d_ws : out;  // fallback: carve sim region
    float* z      = ws;
    float* a_src  = ws + 640000;
    float* a_dst  = ws + 650000;
    int*   cnt    = (int*)(ws + 660000);
    int*   offs   = (int*)(ws + 670000);    // 10001
    int*   cursor = (int*)(ws + 680001);
    int*   srcs   = (int*)(ws + 690001);
    float* ew     = ws + 1020001;

    hipMemsetAsync(cnt, 0, N_NODES * sizeof(int), stream);

    dense_gat_kernel<<<N_NODES / 8, 128, 0, stream>>>(x, dw, db, gw, asv, adv,
                                                      z, a_src, a_dst);

    const int total_edges = E_EDGES + N_NODES;
    const int eb = (total_edges + 255) / 256;
    count_kernel<<<eb, 256, 0, stream>>>(ei, cnt);
    scan_kernel<<<1, 256, 0, stream>>>(cnt, offs, cursor);
    scatter_kernel<<<eb, 256, 0, stream>>>(ei, a_src, a_dst, cursor, srcs, ew);
    aggregate_kernel<<<(N_NODES * 64 + 255) / 256, 256, 0, stream>>>(
        offs, srcs, ew, z, gb, emb);

    dim3 grid((N_NODES + 127) / 128, (N_NODES + 127) / 128);
    sim_kernel<<<grid, 256, 0, stream>>>(emb, sim);
}

// Round 4
// 563.285 us; speedup vs baseline: 1.4958x; 1.0314x over previous
//
#include <hip/hip_runtime.h>
#include <math.h>

#define N_NODES 10000
#define E_EDGES 320000
#define IN_DIM 128
#define EMB 128
#define HID 64
#define NEG_SLOPE 0.2f

typedef __attribute__((ext_vector_type(8))) short short8;     // 8 bf16 (4 VGPR)
typedef __attribute__((ext_vector_type(4))) short short4_t;   // 4 bf16
typedef __attribute__((ext_vector_type(4))) float floatx4;    // 4 fp32

// fp32 -> bf16 bits, round-to-nearest-even
__device__ __forceinline__ short f2bf(float f) {
    unsigned u = __float_as_uint(f);
    unsigned r = u + 0x7fffu + ((u >> 16) & 1u);
    return (short)(r >> 16);
}

// ---------------------------------------------------------------------------
// Kernel A: h = relu(x @ dense_w + b); z = h @ gat_w.
// 256 threads, 16 rows/block (625 blocks), all threads active in both GEMMs.
// ---------------------------------------------------------------------------
__global__ __launch_bounds__(256) void dense_gat_kernel(
    const float* __restrict__ x, const float* __restrict__ dw,
    const float* __restrict__ db, const float* __restrict__ gw,
    float* __restrict__ z)
{
    __shared__ float xs[16][IN_DIM];
    __shared__ float hs[16][EMB];
    const int t = threadIdx.x;
    const int row0 = blockIdx.x * 16;   // 10000 % 16 == 0

    #pragma unroll
    for (int r = 0; r < 2; ++r) {
        const int idx = t + r * 256;           // 0..511 float4 slots
        const int row = idx >> 5, c4 = idx & 31;
        *(floatx4*)&xs[row][c4 * 4] =
            *(const floatx4*)&x[(row0 + row) * IN_DIM + c4 * 4];
    }
    __syncthreads();

    // GEMM1: col = t&127, rows (t>>7)*8 .. +8
    {
        const int col = t & 127, rb = (t >> 7) * 8;
        float acc[8];
        const float bias = db[col];
        #pragma unroll
        for (int r = 0; r < 8; ++r) acc[r] = bias;
        for (int j = 0; j < IN_DIM; ++j) {
            const float wj = dw[j * EMB + col];
            #pragma unroll
            for (int r = 0; r < 8; ++r) acc[r] = fmaf(xs[rb + r][j], wj, acc[r]);
        }
        #pragma unroll
        for (int r = 0; r < 8; ++r) hs[rb + r][col] = fmaxf(acc[r], 0.f);
    }
    __syncthreads();

    // GEMM2: col = t&63, rows (t>>6)*4 .. +4
    {
        const int col = t & 63, rb = (t >> 6) * 4;
        float acc[4] = {0.f, 0.f, 0.f, 0.f};
        for (int k = 0; k < EMB; ++k) {
            const float g = gw[k * HID + col];
            #pragma unroll
            for (int r = 0; r < 4; ++r) acc[r] = fmaf(hs[rb + r][k], g, acc[r]);
        }
        #pragma unroll
        for (int r = 0; r < 4; ++r) z[(row0 + rb + r) * HID + col] = acc[r];
    }
}

// ---------------------------------------------------------------------------
// a_src = z.att_src, a_dst = z.att_dst — one wave per node.
// ---------------------------------------------------------------------------
__global__ __launch_bounds__(256) void att_kernel(
    const float* __restrict__ z, const float* __restrict__ asv,
    const float* __restrict__ adv, float* __restrict__ a_src,
    float* __restrict__ a_dst)
{
    const int wid  = (blockIdx.x * blockDim.x + threadIdx.x) >> 6;
    const int lane = threadIdx.x & 63;
    if (wid >= N_NODES) return;
    const float zv = z[wid * HID + lane];
    float ps = zv * asv[lane];
    float pd = zv * adv[lane];
    #pragma unroll
    for (int off = 32; off > 0; off >>= 1) {
        ps += __shfl_down(ps, off, 64);
        pd += __shfl_down(pd, off, 64);
    }
    if (lane == 0) { a_src[wid] = ps; a_dst[wid] = pd; }
}

// ---------------------------------------------------------------------------
// Edge pipeline: counting sort by dst, then atomic-free aggregation.
// ---------------------------------------------------------------------------
__global__ __launch_bounds__(256) void count_kernel(
    const int* __restrict__ ei, int* __restrict__ cnt)
{
    const int e = blockIdx.x * blockDim.x + threadIdx.x;
    const int total = E_EDGES + N_NODES;
    if (e >= total) return;
    int s, d;
    if (e < E_EDGES) { s = ei[e]; d = ei[E_EDGES + e]; }
    else             { s = d = e - E_EDGES; }
    if ((unsigned)s >= N_NODES || (unsigned)d >= N_NODES) return;
    atomicAdd(&cnt[d], 1);
}

// single block, 256 threads, 40 items each (10240 >= 10000)
__global__ __launch_bounds__(256) void scan_kernel(
    const int* __restrict__ cnt, int* __restrict__ offs, int* __restrict__ cursor)
{
    __shared__ int part[256];
    const int t = threadIdx.x;
    const int base = t * 40;
    int vals[40];
    int local = 0;
    #pragma unroll
    for (int i = 0; i < 40; ++i) {
        const int idx = base + i;
        const int c = (idx < N_NODES) ? cnt[idx] : 0;
        vals[i] = c;
        local += c;
    }
    part[t] = local;
    __syncthreads();
    for (int off = 1; off < 256; off <<= 1) {   // Hillis-Steele inclusive
        const int v = (t >= off) ? part[t - off] : 0;
        __syncthreads();
        part[t] += v;
        __syncthreads();
    }
    int running = (t == 0) ? 0 : part[t - 1];   // exclusive base
    #pragma unroll
    for (int i = 0; i < 40; ++i) {
        const int idx = base + i;
        if (idx < N_NODES) { offs[idx] = running; cursor[idx] = running; }
        running += vals[i];
    }
    if (t == 255) offs[N_NODES] = running;
}

__global__ __launch_bounds__(256) void scatter_kernel(
    const int* __restrict__ ei, const float* __restrict__ a_src,
    const float* __restrict__ a_dst, int* __restrict__ cursor,
    int* __restrict__ srcs, float* __restrict__ ew)
{
    const int e = blockIdx.x * blockDim.x + threadIdx.x;
    const int total = E_EDGES + N_NODES;
    if (e >= total) return;
    int s, d;
    if (e < E_EDGES) { s = ei[e]; d = ei[E_EDGES + e]; }
    else             { s = d = e - E_EDGES; }
    if ((unsigned)s >= N_NODES || (unsigned)d >= N_NODES) return;
    float v = a_src[s] + a_dst[d];
    v = (v > 0.f) ? v : NEG_SLOPE * v;
    const float w = __expf(v);          // max-shift skipped: |v| small, fp32 safe
    const int pos = atomicAdd(&cursor[d], 1);
    srcs[pos] = s;
    ew[pos]   = w;
}

// one wave per node; lane = feature dim. No atomics.
__global__ __launch_bounds__(256) void aggregate_kernel(
    const int* __restrict__ offs, const int* __restrict__ srcs,
    const float* __restrict__ ew, const float* __restrict__ z,
    const float* __restrict__ gb, float* __restrict__ emb)
{
    const int wid  = (blockIdx.x * blockDim.x + threadIdx.x) >> 6;
    const int lane = threadIdx.x & 63;
    if (wid >= N_NODES) return;
    const int beg = offs[wid], end = offs[wid + 1];
    float acc = 0.f, sw = 0.f;
    for (int i = beg; i < end; ++i) {
        const int s   = srcs[i];        // broadcast across the wave
        const float w = ew[i];
        acc = fmaf(w, z[s * HID + lane], acc);
        sw += w;
    }
    emb[wid * HID + lane] = acc / sw + gb[lane];  // every node has a self loop
}

// ---------------------------------------------------------------------------
// Kernel D: sim = sigmoid(emb @ emb^T) via bf16 MFMA, LDS-staged.
// 128x128 block, 4 waves of 64x64 (4x4 subtiles of 16x16x32). Both tiles
// converted to bf16 ONCE per block into LDS (stride 72 shorts = 144 B ->
// ds_read_b128 fragment reads at 2-way bank alias = free). bfrag cycles
// through 2 registers inside the tj loop to keep VGPR ~140 (3 waves/SIMD).
// A frag: A[m=lane&15][k=quad*8+j]; B frag: B[k=quad*8+j][n=lane&15];
// C/D: col=lane&15, row=quad*4+reg. [m89 layouts, validated in R3]
// ---------------------------------------------------------------------------
#define SROW 72
__global__ __launch_bounds__(256) void sim_kernel(
    const float* __restrict__ emb, float* __restrict__ sim)
{
    __shared__ short As[128 * SROW];
    __shared__ short Bs[128 * SROW];
    const int t    = threadIdx.x;
    const int lane = t & 63;
    const int wave = t >> 6;                 // 0..3
    const int wm   = (wave >> 1) * 64;
    const int wn   = (wave & 1) * 64;
    const int l15  = lane & 15;
    const int quad = lane >> 4;              // 0..3

    // ---- stage both tiles as bf16 into LDS (8 rounds x 256 thr x float4) ----
    #pragma unroll
    for (int round = 0; round < 8; ++round) {
        const int idx = t + round * 256;     // 0..2047
        const int row = idx >> 4, c4 = idx & 15;
        int gr = blockIdx.y * 128 + row; if (gr > N_NODES - 1) gr = N_NODES - 1;
        int gc = blockIdx.x * 128 + row; if (gc > N_NODES - 1) gc = N_NODES - 1;
        const floatx4 a = *(const floatx4*)&emb[gr * HID + c4 * 4];
        const floatx4 b = *(const floatx4*)&emb[gc * HID + c4 * 4];
        short4_t sa, sb;
        #pragma unroll
        for (int j = 0; j < 4; ++j) { sa[j] = f2bf(a[j]); sb[j] = f2bf(b[j]); }
        *(short4_t*)&As[row * SROW + c4 * 4] = sa;
        *(short4_t*)&Bs[row * SROW + c4 * 4] = sb;
    }
    __syncthreads();

    // ---- fragments + MFMA ----
    short8 afrag[4][2];
    #pragma unroll
    for (int ti = 0; ti < 4; ++ti)
        #pragma unroll
        for (int ks = 0; ks < 2; ++ks)
            afrag[ti][ks] = *(const short8*)&As[(wm + ti * 16 + l15) * SROW +
                                                ks * 32 + quad * 8];

    floatx4 acc[4][4];
    const floatx4 zero = {0.f, 0.f, 0.f, 0.f};
    #pragma unroll
    for (int ti = 0; ti < 4; ++ti)
        #pragma unroll
        for (int tj = 0; tj < 4; ++tj) acc[ti][tj] = zero;

    #pragma unroll
    for (int tj = 0; tj < 4; ++tj) {
        const short8 bf0 = *(const short8*)&Bs[(wn + tj * 16 + l15) * SROW + quad * 8];
        const short8 bf1 = *(const short8*)&Bs[(wn + tj * 16 + l15) * SROW + 32 + quad * 8];
        #pragma unroll
        for (int ti = 0; ti < 4; ++ti) {
            acc[ti][tj] = __builtin_amdgcn_mfma_f32_16x16x32_bf16(
                afrag[ti][0], bf0, acc[ti][tj], 0, 0, 0);
            acc[ti][tj] = __builtin_amdgcn_mfma_f32_16x16x32_bf16(
                afrag[ti][1], bf1, acc[ti][tj], 0, 0, 0);
        }
    }

    // ---- sigmoid epilogue ----
    #pragma unroll
    for (int ti = 0; ti < 4; ++ti) {
        #pragma unroll
        for (int reg = 0; reg < 4; ++reg) {
            const int gr = blockIdx.y * 128 + wm + ti * 16 + quad * 4 + reg;
            if (gr >= N_NODES) continue;
            const size_t rowoff = (size_t)gr * N_NODES;
            #pragma unroll
            for (int tj = 0; tj < 4; ++tj) {
                const int gc = blockIdx.x * 128 + wn + tj * 16 + l15;
                if (gc < N_NODES) {
                    const float v = acc[ti][tj][reg];
                    sim[rowoff + gc] = __builtin_amdgcn_rcpf(1.f + __expf(-v));
                }
            }
        }
    }
}

// ---------------------------------------------------------------------------
extern "C" void kernel_launch(void* const* d_in, const int* in_sizes, int n_in,
                              void* d_out, int out_size, void* d_ws, size_t ws_size,
                              hipStream_t stream)
{
    const float* x   = (const float*)d_in[0];
    const int*   ei  = (const int*)d_in[1];   // edge_index int32 [2,E]
    const float* dw  = (const float*)d_in[2];
    const float* db  = (const float*)d_in[3];
    const float* gw  = (const float*)d_in[4];
    const float* asv = (const float*)d_in[5];
    const float* adv = (const float*)d_in[6];
    const float* gb  = (const float*)d_in[7];

    float* out = (float*)d_out;
    float* sim = out;                                   // [N*N]
    float* emb = out + (size_t)N_NODES * N_NODES;       // [N*HID]

    // Scratch (floats/ints, all dead before sim_kernel):
    // z 640000 | a_src 10000 | a_dst 10000 | cnt 10000 | offs 10001 |
    // cursor 10000 | srcs 330000 | ew 330000  => 1,350,001 * 4B ~= 5.4 MB
    const size_t need = 1350001u * sizeof(float);
    float* ws = (ws_size >= need) ? (float*)d_ws : out;  // fallback: carve sim region
    float* z      = ws;
    float* a_src  = ws + 640000;
    float* a_dst  = ws + 650000;
    int*   cnt    = (int*)(ws + 660000);
    int*   offs   = (int*)(ws + 670000);    // 10001
    int*   cursor = (int*)(ws + 680001);
    int*   srcs   = (int*)(ws + 690001);
    float* ew     = ws + 1020001;

    hipMemsetAsync(cnt, 0, N_NODES * sizeof(int), stream);

    dense_gat_kernel<<<N_NODES / 16, 256, 0, stream>>>(x, dw, db, gw, z);
    att_kernel<<<(N_NODES * 64 + 255) / 256, 256, 0, stream>>>(z, asv, adv,
                                                               a_src, a_dst);

    const int total_edges = E_EDGES + N_NODES;
    const int eb = (total_edges + 255) / 256;
    count_kernel<<<eb, 256, 0, stream>>>(ei, cnt);
    scan_kernel<<<1, 256, 0, stream>>>(cnt, offs, cursor);
    scatter_kernel<<<eb, 256, 0, stream>>>(ei, a_src, a_dst, cursor, srcs, ew);
    aggregate_kernel<<<(N_NODES * 64 + 255) / 256, 256, 0, stream>>>(
        offs, srcs, ew, z, gb, emb);

    dim3 grid((N_NODES + 127) / 128, (N_NODES + 127) / 128);
    sim_kernel<<<grid, 256, 0, stream>>>(emb, sim);
}